// Round 6
// baseline (312.761 us; speedup 1.0000x reference)
//
#include <hip/hip_runtime.h>
#include <cmath>

#define NUM_CLS 58

typedef float v2f __attribute__((ext_vector_type(2)));

// ---------------- merged prep: binarize w1/w2/w3/w4 ----------------
// blocks 0..1151 -> w1, 1152..2303 -> w2, 2304..3455 -> w3, 3456..3583 -> w4
__global__ void prep_all(const float* __restrict__ w1, const float* __restrict__ w2,
                         const float* __restrict__ w3, const float* __restrict__ w4,
                         unsigned long long* __restrict__ wb1, unsigned long long* __restrict__ wb2,
                         unsigned long long* __restrict__ wb3, unsigned long long* __restrict__ wb4) {
    int id = blockIdx.x, lane = threadIdx.x;
    if (id < 3456) {
        const float* w = id < 1152 ? w1 : (id < 2304 ? w2 : w3);
        unsigned long long* o = id < 1152 ? wb1 : (id < 2304 ? wb2 : wb3);
        int item = id % 1152;
        int oc = item / 9, k = item % 9;
        const float* base = w + (size_t)oc * 1152 + k;   // element ic at base[ic*9]
        unsigned long long b0 = __ballot(base[lane * 9] >= 0.f);
        unsigned long long b1 = __ballot(base[(lane + 64) * 9] >= 0.f);
        if (lane == 0) { o[item * 2] = b0; o[item * 2 + 1] = b1; }
    } else {
        int oc = id - 3456;
        unsigned long long b0 = __ballot(w4[oc * 128 + lane] >= 0.f);
        unsigned long long b1 = __ballot(w4[oc * 128 + lane + 64] >= 0.f);
        if (lane == 0) { wb4[oc * 2] = b0; wb4[oc * 2 + 1] = b1; }
    }
}

// ---- one block per batch element: conv0+pool -> binconv1+pool -> binconv2+pool
//      -> binconv3 -> binconv4 -> relu -> w5 -> softmax ----
__global__ __launch_bounds__(256) void fused_net(
    const float* __restrict__ x, const float* __restrict__ w0,
    const unsigned long long* __restrict__ wb1, const unsigned long long* __restrict__ wb2,
    const unsigned long long* __restrict__ wb3, const unsigned long long* __restrict__ wb4,
    const float* __restrict__ w5, float* __restrict__ out) {
    __shared__ unsigned long long bits1[450];  // [15*15][2]
    __shared__ unsigned long long bits2[72];   // [6*6][2]
    __shared__ unsigned long long bits3[18];   // [3*3][2]
    __shared__ unsigned long long bits4[2];
    __shared__ float r_s[128];
    __shared__ float l_s[NUM_CLS];
    __shared__ float e_s[NUM_CLS];

    int b = blockIdx.x;
    int tid = threadIdx.x;
    int lane = tid & 63;

    // ================= phase 0: float conv0 + maxpool2 + sign-pack =================
    // lane = oc (and oc+64 in the .y half); pixel index is wave-uniform -> patch
    // loads are uniform (SMEM/L1-broadcast), weights live in per-lane VGPRs.
    {
        int wv = __builtin_amdgcn_readfirstlane(tid >> 6);   // provably wave-uniform
        const float* xb = x + (size_t)b * 3072;
        v2f w2[27];                       // {w[lane][j], w[lane+64][j]} — loaded ONCE
#pragma unroll
        for (int j = 0; j < 27; j++)
            w2[j] = (v2f){ w0[lane * 27 + j], w0[(lane + 64) * 27 + j] };

        for (int p = wv; p < 225; p += 4) {
            int py = p / 15, px = p % 15;
            float pa[48];                 // 4x4 patch x 3 ch — wave-uniform values
#pragma unroll
            for (int c = 0; c < 3; c++)
#pragma unroll
                for (int yy = 0; yy < 4; yy++)
#pragma unroll
                    for (int xx = 0; xx < 4; xx++)
                        pa[c * 16 + yy * 4 + xx] = xb[c * 1024 + (2 * py + yy) * 32 + 2 * px + xx];

            v2f a00 = {0.f, 0.f}, a01 = {0.f, 0.f}, a10 = {0.f, 0.f}, a11 = {0.f, 0.f};
#pragma unroll
            for (int c = 0; c < 3; c++)
#pragma unroll
                for (int ky = 0; ky < 3; ky++)
#pragma unroll
                    for (int kx = 0; kx < 3; kx++) {
                        v2f w = w2[c * 9 + ky * 3 + kx];
                        float x00 = pa[c * 16 + ky * 4 + kx];
                        float x01 = pa[c * 16 + ky * 4 + kx + 1];
                        float x10 = pa[c * 16 + (ky + 1) * 4 + kx];
                        float x11 = pa[c * 16 + (ky + 1) * 4 + kx + 1];
                        a00 = __builtin_elementwise_fma((v2f){x00, x00}, w, a00);
                        a01 = __builtin_elementwise_fma((v2f){x01, x01}, w, a01);
                        a10 = __builtin_elementwise_fma((v2f){x10, x10}, w, a10);
                        a11 = __builtin_elementwise_fma((v2f){x11, x11}, w, a11);
                    }
            bool pos_lo = (a00.x >= 0.f) | (a01.x >= 0.f) | (a10.x >= 0.f) | (a11.x >= 0.f);
            bool pos_hi = (a00.y >= 0.f) | (a01.y >= 0.f) | (a10.y >= 0.f) | (a11.y >= 0.f);
            bool need_lo = (fabsf(a00.x) < 1e-4f) | (fabsf(a01.x) < 1e-4f) |
                           (fabsf(a10.x) < 1e-4f) | (fabsf(a11.x) < 1e-4f);
            bool need_hi = (fabsf(a00.y) < 1e-4f) | (fabsf(a01.y) < 1e-4f) |
                           (fabsf(a10.y) < 1e-4f) | (fabsf(a11.y) < 1e-4f);
            // -------- rare cold path: redo borderline lanes in f64 --------
            if (__builtin_expect(__ballot(need_lo | need_hi) != 0ull, 0)) {
                if (need_lo | need_hi) {
                    double s00l = 0, s01l = 0, s10l = 0, s11l = 0;
                    double s00h = 0, s01h = 0, s10h = 0, s11h = 0;
#pragma unroll
                    for (int c = 0; c < 3; c++)
#pragma unroll
                        for (int ky = 0; ky < 3; ky++)
#pragma unroll
                            for (int kx = 0; kx < 3; kx++) {
                                v2f w = w2[c * 9 + ky * 3 + kx];
                                double wl = (double)w.x, wh = (double)w.y;
                                double x00 = (double)pa[c * 16 + ky * 4 + kx];
                                double x01 = (double)pa[c * 16 + ky * 4 + kx + 1];
                                double x10 = (double)pa[c * 16 + (ky + 1) * 4 + kx];
                                double x11 = (double)pa[c * 16 + (ky + 1) * 4 + kx + 1];
                                s00l += x00 * wl; s01l += x01 * wl; s10l += x10 * wl; s11l += x11 * wl;
                                s00h += x00 * wh; s01h += x01 * wh; s10h += x10 * wh; s11h += x11 * wh;
                            }
                    if (need_lo) pos_lo = (s00l >= 0.0) | (s01l >= 0.0) | (s10l >= 0.0) | (s11l >= 0.0);
                    if (need_hi) pos_hi = (s00h >= 0.0) | (s01h >= 0.0) | (s10h >= 0.0) | (s11h >= 0.0);
                }
            }
            unsigned long long m0 = __ballot(pos_lo);   // bit i = sign of oc=i
            unsigned long long m1 = __ballot(pos_hi);   // bit i = sign of oc=i+64
            if (lane == 0) { bits1[p * 2] = m0; bits1[p * 2 + 1] = m1; }
        }
    }
    __syncthreads();

    int wave = tid >> 6, half = wave & 1, pair = wave >> 1;
    int oc = half * 64 + lane;

    // ================= phase 1: binconv1 (15->13) + maxpool2 (->6) =================
    {
        unsigned long long wr[18];
#pragma unroll
        for (int j = 0; j < 18; j++) wr[j] = wb1[oc * 18 + j];
        for (int p = pair; p < 36; p += 2) {
            int py = p / 6, px = p % 6;
            unsigned long long xp[4][4][2];
#pragma unroll
            for (int yy = 0; yy < 4; yy++)
#pragma unroll
                for (int xx = 0; xx < 4; xx++) {
                    int idx = ((2 * py + yy) * 15 + (2 * px + xx)) * 2;
                    xp[yy][xx][0] = bits1[idx];
                    xp[yy][xx][1] = bits1[idx + 1];
                }
            bool pos = false;
#pragma unroll
            for (int dy = 0; dy < 2; dy++)
#pragma unroll
                for (int dx = 0; dx < 2; dx++) {
                    int P = 0;
#pragma unroll
                    for (int ky = 0; ky < 3; ky++)
#pragma unroll
                        for (int kx = 0; kx < 3; kx++) {
                            P += __popcll(xp[dy + ky][dx + kx][0] ^ wr[(ky * 3 + kx) * 2]);
                            P += __popcll(xp[dy + ky][dx + kx][1] ^ wr[(ky * 3 + kx) * 2 + 1]);
                        }
                    pos |= (P <= 576);   // 1152 - 2P >= 0
                }
            unsigned long long m = __ballot(pos);
            if (lane == 0) bits2[p * 2 + half] = m;
        }
    }
    __syncthreads();

    // ================= phase 2: binconv2 (6->4) + maxpool(2,s1) (->3) =================
    {
        unsigned long long wr[18];
#pragma unroll
        for (int j = 0; j < 18; j++) wr[j] = wb2[oc * 18 + j];
        for (int p = pair; p < 9; p += 2) {
            int py = p / 3, px = p % 3;
            bool pos = false;
#pragma unroll
            for (int dy = 0; dy < 2; dy++)
#pragma unroll
                for (int dx = 0; dx < 2; dx++) {
                    int P = 0;
#pragma unroll
                    for (int ky = 0; ky < 3; ky++)
#pragma unroll
                        for (int kx = 0; kx < 3; kx++) {
                            int idx = ((py + dy + ky) * 6 + (px + dx + kx)) * 2;
                            P += __popcll(bits2[idx] ^ wr[(ky * 3 + kx) * 2]);
                            P += __popcll(bits2[idx + 1] ^ wr[(ky * 3 + kx) * 2 + 1]);
                        }
                    pos |= (P <= 576);
                }
            unsigned long long m = __ballot(pos);
            if (lane == 0) bits3[p * 2 + half] = m;
        }
    }
    __syncthreads();

    // ================= phase 3: binconv3 + binconv4 + relu + w5 + softmax =================
    if (tid < 128) {
        int P = 0;
#pragma unroll
        for (int k = 0; k < 9; k++) {
            P += __popcll(bits3[k * 2] ^ wb3[tid * 18 + k * 2]);
            P += __popcll(bits3[k * 2 + 1] ^ wb3[tid * 18 + k * 2 + 1]);
        }
        unsigned long long m = __ballot(P <= 576);
        if ((tid & 63) == 0) bits4[tid >> 6] = m;
    }
    __syncthreads();
    if (tid < 128) {
        unsigned long long i0 = bits4[0], i1 = bits4[1];
        int v = 128 - 2 * (int)(__popcll(i0 ^ wb4[tid * 2]) + __popcll(i1 ^ wb4[tid * 2 + 1]));
        r_s[tid] = v > 0 ? (float)v : 0.f;   // relu
    }
    __syncthreads();
    if (tid < NUM_CLS) {
        float l = 0.f;
#pragma unroll 8
        for (int k = 0; k < 128; k++) l = fmaf(w5[tid * 128 + k], r_s[k], l);
        l_s[tid] = l;
    }
    __syncthreads();
    if (tid < NUM_CLS) {
        float mx = -1e30f;
        for (int k = 0; k < NUM_CLS; k++) mx = fmaxf(mx, l_s[k]);
        e_s[tid] = expf(l_s[tid] - mx);
    }
    __syncthreads();
    if (tid < NUM_CLS) {
        float sum = 0.f;
        for (int k = 0; k < NUM_CLS; k++) sum += e_s[k];
        out[(size_t)b * NUM_CLS + tid] = e_s[tid] / sum;
    }
}

extern "C" void kernel_launch(void* const* d_in, const int* in_sizes, int n_in,
                              void* d_out, int out_size, void* d_ws, size_t ws_size,
                              hipStream_t stream) {
    const float* x  = (const float*)d_in[0];
    const float* w0 = (const float*)d_in[1];
    const float* w1 = (const float*)d_in[2];
    const float* w2 = (const float*)d_in[3];
    const float* w3 = (const float*)d_in[4];
    const float* w4 = (const float*)d_in[5];
    const float* w5 = (const float*)d_in[6];
    float* out = (float*)d_out;

    int B = in_sizes[0] / 3072;   // 1024

    size_t off = 0;
    auto carve = [&](size_t bytes) {
        void* p = (char*)d_ws + off;
        off += (bytes + 255) & ~(size_t)255;
        return p;
    };
    unsigned long long* wb1 = (unsigned long long*)carve(1152 * 2 * 8);
    unsigned long long* wb2 = (unsigned long long*)carve(1152 * 2 * 8);
    unsigned long long* wb3 = (unsigned long long*)carve(1152 * 2 * 8);
    unsigned long long* wb4 = (unsigned long long*)carve(128 * 2 * 8);
    (void)ws_size; (void)n_in; (void)out_size;

    prep_all<<<3584, 64, 0, stream>>>(w1, w2, w3, w4, wb1, wb2, wb3, wb4);
    fused_net<<<B, 256, 0, stream>>>(x, w0, wb1, wb2, wb3, wb4, w5, out);
}

// Round 7
// 230.901 us; speedup vs baseline: 1.3545x; 1.3545x over previous
//
#include <hip/hip_runtime.h>
#include <cmath>

#define NUM_CLS 58

typedef float v2f __attribute__((ext_vector_type(2)));

// acc = splat(act[PAR]) * w + acc   — packed fp32 FMA, splat via op_sel (zero movs)
template <int PAR>
__device__ __forceinline__ void pkfma_splat(v2f& acc, v2f act, v2f w) {
    if constexpr (PAR == 0)
        asm("v_pk_fma_f32 %0, %1, %2, %0 op_sel:[0,0,0] op_sel_hi:[0,1,1]"
            : "+v"(acc) : "v"(act), "v"(w));
    else
        asm("v_pk_fma_f32 %0, %1, %2, %0 op_sel:[1,0,0] op_sel_hi:[1,1,1]"
            : "+v"(acc) : "v"(act), "v"(w));
}

// ---------------- merged prep: binarize w1/w2/w3/w4 ----------------
__global__ void prep_all(const float* __restrict__ w1, const float* __restrict__ w2,
                         const float* __restrict__ w3, const float* __restrict__ w4,
                         unsigned long long* __restrict__ wb1, unsigned long long* __restrict__ wb2,
                         unsigned long long* __restrict__ wb3, unsigned long long* __restrict__ wb4) {
    int id = blockIdx.x, lane = threadIdx.x;
    if (id < 3456) {
        const float* w = id < 1152 ? w1 : (id < 2304 ? w2 : w3);
        unsigned long long* o = id < 1152 ? wb1 : (id < 2304 ? wb2 : wb3);
        int item = id % 1152;
        int oc = item / 9, k = item % 9;
        const float* base = w + (size_t)oc * 1152 + k;   // element ic at base[ic*9]
        unsigned long long b0 = __ballot(base[lane * 9] >= 0.f);
        unsigned long long b1 = __ballot(base[(lane + 64) * 9] >= 0.f);
        if (lane == 0) { o[item * 2] = b0; o[item * 2 + 1] = b1; }
    } else {
        int oc = id - 3456;
        unsigned long long b0 = __ballot(w4[oc * 128 + lane] >= 0.f);
        unsigned long long b1 = __ballot(w4[oc * 128 + lane + 64] >= 0.f);
        if (lane == 0) { wb4[oc * 2] = b0; wb4[oc * 2 + 1] = b1; }
    }
}

// ---- one block per batch element: conv0+pool -> binconv1+pool -> binconv2+pool
//      -> binconv3 -> binconv4 -> relu -> w5 -> softmax ----
__global__ __launch_bounds__(256) void fused_net(
    const float* __restrict__ x, const float* __restrict__ w0,
    const unsigned long long* __restrict__ wb1, const unsigned long long* __restrict__ wb2,
    const unsigned long long* __restrict__ wb3, const unsigned long long* __restrict__ wb4,
    const float* __restrict__ w5, float* __restrict__ out) {
    __shared__ float xs[3072];                 // input image (12 KB)
    __shared__ unsigned long long bits1[450];  // [15*15][2]
    __shared__ unsigned long long bits2[72];   // [6*6][2]
    __shared__ unsigned long long bits3[18];   // [3*3][2]
    __shared__ unsigned long long bits4[2];
    __shared__ float r_s[128];
    __shared__ float l_s[NUM_CLS];
    __shared__ float e_s[NUM_CLS];

    int b = blockIdx.x;
    int tid = threadIdx.x;
    int lane = tid & 63;

    // ================= phase 0: float conv0 + maxpool2 + sign-pack =================
    // lane = oc pair {lane, lane+64}: weights in per-lane VGPRs (loaded ONCE);
    // activations staged in LDS, read wave-uniform (broadcast, conflict-free);
    // packed fp32 FMA with op_sel splat; sign-pack via 2 ballots.
    {
        const float* xb = x + (size_t)b * 3072;
        for (int i = tid; i < 3072; i += 256) xs[i] = xb[i];   // coalesced
        v2f w2[27];                       // {w[lane][j], w[lane+64][j]}
#pragma unroll
        for (int j = 0; j < 27; j++)
            w2[j] = (v2f){ w0[lane * 27 + j], w0[(lane + 64) * 27 + j] };
        __syncthreads();

        int wv = __builtin_amdgcn_readfirstlane(tid >> 6);
        const v2f* xs2 = (const v2f*)xs;
        for (int p = wv; p < 225; p += 4) {
            int py = p / 15, px = p % 15;
            // patch: 3 ch x 4 rows x 4 cols as v2f pairs (cols {0,1},{2,3})
            v2f xp2[24];
#pragma unroll
            for (int c = 0; c < 3; c++)
#pragma unroll
                for (int yy = 0; yy < 4; yy++) {
                    int base2 = (c * 1024 + (2 * py + yy) * 32) / 2 + px;  // uniform addr
                    xp2[c * 8 + yy * 2 + 0] = xs2[base2];
                    xp2[c * 8 + yy * 2 + 1] = xs2[base2 + 1];
                }
            v2f a00 = {0.f, 0.f}, a01 = {0.f, 0.f}, a10 = {0.f, 0.f}, a11 = {0.f, 0.f};
#pragma unroll
            for (int c = 0; c < 3; c++)
#pragma unroll
                for (int ky = 0; ky < 3; ky++)
#pragma unroll
                    for (int kx = 0; kx < 3; kx++) {
                        v2f w = w2[c * 9 + ky * 3 + kx];
                        // pool offsets (dy,dx); window col = dx+kx, row = dy+ky
#pragma unroll
                        for (int dy = 0; dy < 2; dy++) {
                            v2f r0 = xp2[c * 8 + (ky + dy) * 2 + ((kx + 0) >> 1)];
                            v2f r1 = xp2[c * 8 + (ky + dy) * 2 + ((kx + 1) >> 1)];
                            v2f& accA = dy ? a10 : a00;
                            v2f& accB = dy ? a11 : a01;
                            if ((kx & 1) == 0) {
                                pkfma_splat<0>(accA, r0, w);   // col kx even -> word0
                                pkfma_splat<1>(accB, r1, w);   // col kx+1 odd -> word1
                            } else {
                                pkfma_splat<1>(accA, r0, w);
                                pkfma_splat<0>(accB, r1, w);
                            }
                        }
                    }
            bool pos_lo = (a00.x >= 0.f) | (a01.x >= 0.f) | (a10.x >= 0.f) | (a11.x >= 0.f);
            bool pos_hi = (a00.y >= 0.f) | (a01.y >= 0.f) | (a10.y >= 0.f) | (a11.y >= 0.f);
            bool need_lo = (fabsf(a00.x) < 1e-4f) | (fabsf(a01.x) < 1e-4f) |
                           (fabsf(a10.x) < 1e-4f) | (fabsf(a11.x) < 1e-4f);
            bool need_hi = (fabsf(a00.y) < 1e-4f) | (fabsf(a01.y) < 1e-4f) |
                           (fabsf(a10.y) < 1e-4f) | (fabsf(a11.y) < 1e-4f);
            // -------- rare cold path: redo borderline lanes in f64 --------
            if (__builtin_expect(__ballot(need_lo | need_hi) != 0ull, 0)) {
                if (need_lo | need_hi) {
                    double sl[4] = {0, 0, 0, 0}, sh[4] = {0, 0, 0, 0};
#pragma unroll
                    for (int c = 0; c < 3; c++)
#pragma unroll
                        for (int ky = 0; ky < 3; ky++)
#pragma unroll
                            for (int kx = 0; kx < 3; kx++) {
                                v2f w = w2[c * 9 + ky * 3 + kx];
#pragma unroll
                                for (int dy = 0; dy < 2; dy++)
#pragma unroll
                                    for (int dx = 0; dx < 2; dx++) {
                                        int col = kx + dx;
                                        v2f a = xp2[c * 8 + (ky + dy) * 2 + (col >> 1)];
                                        double xv = (double)((col & 1) ? a.y : a.x);
                                        sl[dy * 2 + dx] += xv * (double)w.x;
                                        sh[dy * 2 + dx] += xv * (double)w.y;
                                    }
                            }
                    if (need_lo) pos_lo = (sl[0] >= 0.0) | (sl[1] >= 0.0) | (sl[2] >= 0.0) | (sl[3] >= 0.0);
                    if (need_hi) pos_hi = (sh[0] >= 0.0) | (sh[1] >= 0.0) | (sh[2] >= 0.0) | (sh[3] >= 0.0);
                }
            }
            unsigned long long m0 = __ballot(pos_lo);   // bit i = sign of oc=i
            unsigned long long m1 = __ballot(pos_hi);   // bit i = sign of oc=i+64
            if (lane == 0) { bits1[p * 2] = m0; bits1[p * 2 + 1] = m1; }
        }
    }
    __syncthreads();

    int wave = tid >> 6, half = wave & 1, pair = wave >> 1;
    int oc = half * 64 + lane;

    // ================= phase 1: binconv1 (15->13) + maxpool2 (->6) =================
    {
        unsigned long long wr[18];
#pragma unroll
        for (int j = 0; j < 18; j++) wr[j] = wb1[oc * 18 + j];
        for (int p = pair; p < 36; p += 2) {
            int py = p / 6, px = p % 6;
            unsigned long long xp[4][4][2];
#pragma unroll
            for (int yy = 0; yy < 4; yy++)
#pragma unroll
                for (int xx = 0; xx < 4; xx++) {
                    int idx = ((2 * py + yy) * 15 + (2 * px + xx)) * 2;
                    xp[yy][xx][0] = bits1[idx];
                    xp[yy][xx][1] = bits1[idx + 1];
                }
            bool pos = false;
#pragma unroll
            for (int dy = 0; dy < 2; dy++)
#pragma unroll
                for (int dx = 0; dx < 2; dx++) {
                    int P = 0;
#pragma unroll
                    for (int ky = 0; ky < 3; ky++)
#pragma unroll
                        for (int kx = 0; kx < 3; kx++) {
                            P += __popcll(xp[dy + ky][dx + kx][0] ^ wr[(ky * 3 + kx) * 2]);
                            P += __popcll(xp[dy + ky][dx + kx][1] ^ wr[(ky * 3 + kx) * 2 + 1]);
                        }
                    pos |= (P <= 576);   // 1152 - 2P >= 0
                }
            unsigned long long m = __ballot(pos);
            if (lane == 0) bits2[p * 2 + half] = m;
        }
    }
    __syncthreads();

    // ================= phase 2: binconv2 (6->4) + maxpool(2,s1) (->3) =================
    {
        unsigned long long wr[18];
#pragma unroll
        for (int j = 0; j < 18; j++) wr[j] = wb2[oc * 18 + j];
        for (int p = pair; p < 9; p += 2) {
            int py = p / 3, px = p % 3;
            bool pos = false;
#pragma unroll
            for (int dy = 0; dy < 2; dy++)
#pragma unroll
                for (int dx = 0; dx < 2; dx++) {
                    int P = 0;
#pragma unroll
                    for (int ky = 0; ky < 3; ky++)
#pragma unroll
                        for (int kx = 0; kx < 3; kx++) {
                            int idx = ((py + dy + ky) * 6 + (px + dx + kx)) * 2;
                            P += __popcll(bits2[idx] ^ wr[(ky * 3 + kx) * 2]);
                            P += __popcll(bits2[idx + 1] ^ wr[(ky * 3 + kx) * 2 + 1]);
                        }
                    pos |= (P <= 576);
                }
            unsigned long long m = __ballot(pos);
            if (lane == 0) bits3[p * 2 + half] = m;
        }
    }
    __syncthreads();

    // ================= phase 3: binconv3 + binconv4 + relu + w5 + softmax =================
    if (tid < 128) {
        int P = 0;
#pragma unroll
        for (int k = 0; k < 9; k++) {
            P += __popcll(bits3[k * 2] ^ wb3[tid * 18 + k * 2]);
            P += __popcll(bits3[k * 2 + 1] ^ wb3[tid * 18 + k * 2 + 1]);
        }
        unsigned long long m = __ballot(P <= 576);
        if ((tid & 63) == 0) bits4[tid >> 6] = m;
    }
    __syncthreads();
    if (tid < 128) {
        unsigned long long i0 = bits4[0], i1 = bits4[1];
        int v = 128 - 2 * (int)(__popcll(i0 ^ wb4[tid * 2]) + __popcll(i1 ^ wb4[tid * 2 + 1]));
        r_s[tid] = v > 0 ? (float)v : 0.f;   // relu
    }
    __syncthreads();
    if (tid < NUM_CLS) {
        float l = 0.f;
#pragma unroll 8
        for (int k = 0; k < 128; k++) l = fmaf(w5[tid * 128 + k], r_s[k], l);
        l_s[tid] = l;
    }
    __syncthreads();
    if (tid < NUM_CLS) {
        float mx = -1e30f;
        for (int k = 0; k < NUM_CLS; k++) mx = fmaxf(mx, l_s[k]);
        e_s[tid] = expf(l_s[tid] - mx);
    }
    __syncthreads();
    if (tid < NUM_CLS) {
        float sum = 0.f;
        for (int k = 0; k < NUM_CLS; k++) sum += e_s[k];
        out[(size_t)b * NUM_CLS + tid] = e_s[tid] / sum;
    }
}

extern "C" void kernel_launch(void* const* d_in, const int* in_sizes, int n_in,
                              void* d_out, int out_size, void* d_ws, size_t ws_size,
                              hipStream_t stream) {
    const float* x  = (const float*)d_in[0];
    const float* w0 = (const float*)d_in[1];
    const float* w1 = (const float*)d_in[2];
    const float* w2 = (const float*)d_in[3];
    const float* w3 = (const float*)d_in[4];
    const float* w4 = (const float*)d_in[5];
    const float* w5 = (const float*)d_in[6];
    float* out = (float*)d_out;

    int B = in_sizes[0] / 3072;   // 1024

    size_t off = 0;
    auto carve = [&](size_t bytes) {
        void* p = (char*)d_ws + off;
        off += (bytes + 255) & ~(size_t)255;
        return p;
    };
    unsigned long long* wb1 = (unsigned long long*)carve(1152 * 2 * 8);
    unsigned long long* wb2 = (unsigned long long*)carve(1152 * 2 * 8);
    unsigned long long* wb3 = (unsigned long long*)carve(1152 * 2 * 8);
    unsigned long long* wb4 = (unsigned long long*)carve(128 * 2 * 8);
    (void)ws_size; (void)n_in; (void)out_size;

    prep_all<<<3584, 64, 0, stream>>>(w1, w2, w3, w4, wb1, wb2, wb3, wb4);
    fused_net<<<B, 256, 0, stream>>>(x, w0, wb1, wb2, wb3, wb4, w5, out);
}

// Round 8
// 223.557 us; speedup vs baseline: 1.3990x; 1.0328x over previous
//
#include <hip/hip_runtime.h>
#include <cmath>

#define NUM_CLS 58

typedef _Float16 v8h __attribute__((ext_vector_type(8)));
typedef float v4f __attribute__((ext_vector_type(4)));
union HU { v8h h; uint4 u; };

// ---------------- merged prep: binarize w1/w2/w3/w4 + pack w0 MFMA B-fragments ----------------
// blocks 0..1151 -> w1, 1152..2303 -> w2, 2304..3455 -> w3, 3456..3583 -> w4,
// 3584..3591 -> B-frags: nt = id-3584; lane holds B[k=(lane>>4)*8+j][n=nt*16+(lane&15)]
__global__ void prep_all(const float* __restrict__ w0, const float* __restrict__ w1,
                         const float* __restrict__ w2, const float* __restrict__ w3,
                         const float* __restrict__ w4,
                         unsigned long long* __restrict__ wb1, unsigned long long* __restrict__ wb2,
                         unsigned long long* __restrict__ wb3, unsigned long long* __restrict__ wb4,
                         _Float16* __restrict__ bsig, _Float16* __restrict__ babs) {
    int id = blockIdx.x, lane = threadIdx.x;
    if (id < 3456) {
        const float* w = id < 1152 ? w1 : (id < 2304 ? w2 : w3);
        unsigned long long* o = id < 1152 ? wb1 : (id < 2304 ? wb2 : wb3);
        int item = id % 1152;
        int oc = item / 9, k = item % 9;
        const float* base = w + (size_t)oc * 1152 + k;   // element ic at base[ic*9]
        unsigned long long b0 = __ballot(base[lane * 9] >= 0.f);
        unsigned long long b1 = __ballot(base[(lane + 64) * 9] >= 0.f);
        if (lane == 0) { o[item * 2] = b0; o[item * 2 + 1] = b1; }
    } else if (id < 3584) {
        int oc = id - 3456;
        unsigned long long b0 = __ballot(w4[oc * 128 + lane] >= 0.f);
        unsigned long long b1 = __ballot(w4[oc * 128 + lane + 64] >= 0.f);
        if (lane == 0) { wb4[oc * 2] = b0; wb4[oc * 2 + 1] = b1; }
    } else {
        int nt = id - 3584;                 // 0..7
        int n = nt * 16 + (lane & 15);
        int k0 = (lane >> 4) * 8;
#pragma unroll
        for (int j = 0; j < 8; j++) {
            int k = k0 + j;
            float v = (k < 27) ? w0[n * 27 + k] : 0.f;
            bsig[(nt * 64 + lane) * 8 + j] = (_Float16)v;
            babs[(nt * 64 + lane) * 8 + j] = (_Float16)fabsf(v);
        }
    }
}

// ---- one block per batch element ----
__global__ __launch_bounds__(256) void fused_net(
    const float* __restrict__ x, const float* __restrict__ w0,
    const _Float16* __restrict__ bsigG, const _Float16* __restrict__ babsG,
    const unsigned long long* __restrict__ wb1, const unsigned long long* __restrict__ wb2,
    const unsigned long long* __restrict__ wb3, const unsigned long long* __restrict__ wb4,
    const float* __restrict__ w5, float* __restrict__ out) {
    __shared__ float xs[3072];                 // input image (12 KB)
    __shared__ unsigned char S[14592];         // [mt57][nt4][lane64] sign|flag bits
    __shared__ unsigned long long bits1[450];  // [15*15][2]
    __shared__ unsigned long long bits2[72];
    __shared__ unsigned long long bits3[18];
    __shared__ unsigned long long bits4[2];
    __shared__ float r_s[128];
    __shared__ float l_s[NUM_CLS];
    __shared__ float e_s[NUM_CLS];
    __shared__ unsigned int qcnt;
    __shared__ unsigned int queue[1024];

    int b = blockIdx.x;
    int tid = threadIdx.x;
    int lane = tid & 63, wave = tid >> 6;

    // ================= phase 0: conv0 via f16 MFMA + guard + maxpool2 + pack =================
    {
        const float* xb = x + (size_t)b * 3072;
        for (int i = tid; i < 3072; i += 256) xs[i] = xb[i];   // coalesced

        // per-lane A-gather offsets: k = k0+j -> (c,ky,kx); addr = (oy*32+ox) + off
        int k0 = (lane >> 4) * 8;
        int offj[8];
#pragma unroll
        for (int j = 0; j < 8; j++) {
            int k = k0 + j;
            int c = k / 9, r = (k % 9) / 3, q = k % 3;
            offj[j] = c * 1024 + r * 32 + q;
        }
        const uint4* bs4 = (const uint4*)bsigG;
        const uint4* ba4 = (const uint4*)babsG;
        int col = lane & 15, nt4l = lane >> 4;

        for (int pass = 0; pass < 2; pass++) {     // pass 0: oc 0-63, pass 1: oc 64-127
            if (tid == 0) qcnt = 0;
            __syncthreads();                       // staging/S-reuse + qcnt visible
            HU bfs[4], bfa[4];
#pragma unroll
            for (int nt = 0; nt < 4; nt++) {
                bfs[nt].u = bs4[(pass * 4 + nt) * 64 + lane];
                bfa[nt].u = ba4[(pass * 4 + nt) * 64 + lane];
            }
            for (int mt = wave; mt < 57; mt += 4) {   // M=900 -> 57 tiles of 16
                int m = mt * 16 + (lane & 15);
                int me = m < 900 ? m : 899;           // pad rows read junk, discarded
                int oy = me / 30, ox = me - oy * 30;
                int base = oy * 32 + ox;
                v8h a;
#pragma unroll
                for (int j = 0; j < 8; j++) {
                    float v = (k0 + j < 27) ? xs[base + offj[j]] : 0.f;
                    a[j] = (_Float16)v;
                }
                HU ua; ua.h = a;                      // |A| for the error-bound MFMA
                ua.u.x &= 0x7FFF7FFFu; ua.u.y &= 0x7FFF7FFFu;
                ua.u.z &= 0x7FFF7FFFu; ua.u.w &= 0x7FFF7FFFu;
#pragma unroll
                for (int nt = 0; nt < 4; nt++) {
                    v4f s  = __builtin_amdgcn_mfma_f32_16x16x32_f16(a,    bfs[nt].h, (v4f){0.f,0.f,0.f,0.f}, 0, 0, 0);
                    v4f sa = __builtin_amdgcn_mfma_f32_16x16x32_f16(ua.h, bfa[nt].h, (v4f){0.f,0.f,0.f,0.f}, 0, 0, 0);
                    unsigned int byte = 0;
#pragma unroll
                    for (int reg = 0; reg < 4; reg++) {
                        float bd = fmaf(sa[reg], 1.1e-3f, 1e-5f);   // rigorous f16-rounding bound
                        if (s[reg] >= bd) byte |= 1u << reg;        // certain positive
                        if (fabsf(s[reg]) < bd) byte |= 1u << (4 + reg);  // uncertain
                    }
                    S[(mt * 4 + nt) * 64 + lane] = (unsigned char)byte;
                }
            }
            __syncthreads();
            // ---- pool (OR of signs over 2x2) + optimistic pack + uncertainty queue ----
            for (int p = wave; p < 225; p += 4) {
                int py = p / 15, pxx = p - py * 15;
                int m00 = py * 60 + pxx * 2;
                unsigned int cpAny = 0, fmask = 0;
#pragma unroll
                for (int dm = 0; dm < 4; dm++) {
                    int m = m00 + (dm >> 1) * 30 + (dm & 1);
                    unsigned int bt = S[((m >> 4) * 4 + nt4l) * 64 + (((m & 15) >> 2) << 4) + col];
                    unsigned int bi = m & 3;
                    cpAny |= (bt >> bi) & 1u;
                    fmask |= ((bt >> (4 + bi)) & 1u) << dm;
                }
                unsigned long long mw = __ballot(cpAny != 0);
                if (lane == 0) bits1[p * 2 + pass] = mw;
                if (!cpAny && fmask) {               // only unresolved windows queue (~50/img)
                    unsigned int qi = atomicAdd(&qcnt, 1u);
                    if (qi < 1024) queue[qi] = (unsigned)p | ((unsigned)(pass * 64 + lane) << 8) | (fmask << 16);
                }
            }
            __syncthreads();
            // ---- drain queue: exact f64 signs for uncertain values ----
            unsigned int nq = qcnt < 1024u ? qcnt : 1024u;
            for (unsigned int i = tid; i < nq; i += 256) {
                unsigned int e = queue[i];
                int p = e & 255; int oc = (e >> 8) & 255; unsigned int fm = (e >> 16) & 15u;
                int py = p / 15, pxx = p - py * 15;
                bool pos = false;
#pragma unroll
                for (int dm = 0; dm < 4; dm++) {
                    if (!(fm & (1u << dm))) continue;
                    int m = py * 60 + pxx * 2 + (dm >> 1) * 30 + (dm & 1);
                    int oy = m / 30, ox = m - oy * 30;
                    double sd = 0.0;
#pragma unroll
                    for (int k = 0; k < 27; k++) {
                        int c = k / 9, r = (k % 9) / 3, q = k % 3;
                        sd += (double)xs[c * 1024 + (oy + r) * 32 + ox + q] * (double)w0[oc * 27 + k];
                    }
                    pos |= (sd >= 0.0);
                }
                if (pos) atomicOr(&bits1[p * 2 + (oc >> 6)], 1ull << (oc & 63));
            }
        }
    }
    __syncthreads();

    int wave2 = tid >> 6, half = wave2 & 1, pair = wave2 >> 1;
    int oc = half * 64 + lane;

    // ================= phase 1: binconv1 (15->13) + maxpool2 (->6) =================
    {
        unsigned long long wr[18];
#pragma unroll
        for (int j = 0; j < 18; j++) wr[j] = wb1[oc * 18 + j];
        for (int p = pair; p < 36; p += 2) {
            int py = p / 6, px = p % 6;
            unsigned long long xp[4][4][2];
#pragma unroll
            for (int yy = 0; yy < 4; yy++)
#pragma unroll
                for (int xx = 0; xx < 4; xx++) {
                    int idx = ((2 * py + yy) * 15 + (2 * px + xx)) * 2;
                    xp[yy][xx][0] = bits1[idx];
                    xp[yy][xx][1] = bits1[idx + 1];
                }
            bool pos = false;
#pragma unroll
            for (int dy = 0; dy < 2; dy++)
#pragma unroll
                for (int dx = 0; dx < 2; dx++) {
                    int P = 0;
#pragma unroll
                    for (int ky = 0; ky < 3; ky++)
#pragma unroll
                        for (int kx = 0; kx < 3; kx++) {
                            P += __popcll(xp[dy + ky][dx + kx][0] ^ wr[(ky * 3 + kx) * 2]);
                            P += __popcll(xp[dy + ky][dx + kx][1] ^ wr[(ky * 3 + kx) * 2 + 1]);
                        }
                    pos |= (P <= 576);   // 1152 - 2P >= 0
                }
            unsigned long long m = __ballot(pos);
            if (lane == 0) bits2[p * 2 + half] = m;
        }
    }
    __syncthreads();

    // ================= phase 2: binconv2 (6->4) + maxpool(2,s1) (->3) =================
    {
        unsigned long long wr[18];
#pragma unroll
        for (int j = 0; j < 18; j++) wr[j] = wb2[oc * 18 + j];
        for (int p = pair; p < 9; p += 2) {
            int py = p / 3, px = p % 3;
            bool pos = false;
#pragma unroll
            for (int dy = 0; dy < 2; dy++)
#pragma unroll
                for (int dx = 0; dx < 2; dx++) {
                    int P = 0;
#pragma unroll
                    for (int ky = 0; ky < 3; ky++)
#pragma unroll
                        for (int kx = 0; kx < 3; kx++) {
                            int idx = ((py + dy + ky) * 6 + (px + dx + kx)) * 2;
                            P += __popcll(bits2[idx] ^ wr[(ky * 3 + kx) * 2]);
                            P += __popcll(bits2[idx + 1] ^ wr[(ky * 3 + kx) * 2 + 1]);
                        }
                    pos |= (P <= 576);
                }
            unsigned long long m = __ballot(pos);
            if (lane == 0) bits3[p * 2 + half] = m;
        }
    }
    __syncthreads();

    // ================= phase 3: binconv3 + binconv4 + relu + w5 + softmax =================
    if (tid < 128) {
        int P = 0;
#pragma unroll
        for (int k = 0; k < 9; k++) {
            P += __popcll(bits3[k * 2] ^ wb3[tid * 18 + k * 2]);
            P += __popcll(bits3[k * 2 + 1] ^ wb3[tid * 18 + k * 2 + 1]);
        }
        unsigned long long m = __ballot(P <= 576);
        if ((tid & 63) == 0) bits4[tid >> 6] = m;
    }
    __syncthreads();
    if (tid < 128) {
        unsigned long long i0 = bits4[0], i1 = bits4[1];
        int v = 128 - 2 * (int)(__popcll(i0 ^ wb4[tid * 2]) + __popcll(i1 ^ wb4[tid * 2 + 1]));
        r_s[tid] = v > 0 ? (float)v : 0.f;   // relu
    }
    __syncthreads();
    if (tid < NUM_CLS) {
        float l = 0.f;
#pragma unroll 8
        for (int k = 0; k < 128; k++) l = fmaf(w5[tid * 128 + k], r_s[k], l);
        l_s[tid] = l;
    }
    __syncthreads();
    if (tid < NUM_CLS) {
        float mx = -1e30f;
        for (int k = 0; k < NUM_CLS; k++) mx = fmaxf(mx, l_s[k]);
        e_s[tid] = expf(l_s[tid] - mx);
    }
    __syncthreads();
    if (tid < NUM_CLS) {
        float sum = 0.f;
        for (int k = 0; k < NUM_CLS; k++) sum += e_s[k];
        out[(size_t)b * NUM_CLS + tid] = e_s[tid] / sum;
    }
}

extern "C" void kernel_launch(void* const* d_in, const int* in_sizes, int n_in,
                              void* d_out, int out_size, void* d_ws, size_t ws_size,
                              hipStream_t stream) {
    const float* x  = (const float*)d_in[0];
    const float* w0 = (const float*)d_in[1];
    const float* w1 = (const float*)d_in[2];
    const float* w2 = (const float*)d_in[3];
    const float* w3 = (const float*)d_in[4];
    const float* w4 = (const float*)d_in[5];
    const float* w5 = (const float*)d_in[6];
    float* out = (float*)d_out;

    int B = in_sizes[0] / 3072;   // 1024

    size_t off = 0;
    auto carve = [&](size_t bytes) {
        void* p = (char*)d_ws + off;
        off += (bytes + 255) & ~(size_t)255;
        return p;
    };
    unsigned long long* wb1 = (unsigned long long*)carve(1152 * 2 * 8);
    unsigned long long* wb2 = (unsigned long long*)carve(1152 * 2 * 8);
    unsigned long long* wb3 = (unsigned long long*)carve(1152 * 2 * 8);
    unsigned long long* wb4 = (unsigned long long*)carve(128 * 2 * 8);
    _Float16* bsig = (_Float16*)carve(8 * 64 * 8 * 2);   // MFMA B-frags (signed)
    _Float16* babs = (_Float16*)carve(8 * 64 * 8 * 2);   // MFMA B-frags (abs)
    (void)ws_size; (void)n_in; (void)out_size;

    prep_all<<<3592, 64, 0, stream>>>(w0, w1, w2, w3, w4, wb1, wb2, wb3, wb4, bsig, babs);
    fused_net<<<B, 256, 0, stream>>>(x, w0, bsig, babs, wb1, wb2, wb3, wb4, w5, out);
}

// Round 9
// 219.673 us; speedup vs baseline: 1.4238x; 1.0177x over previous
//
#include <hip/hip_runtime.h>
#include <cmath>

#define NUM_CLS 58

typedef _Float16 v8h __attribute__((ext_vector_type(8)));
typedef float v4f __attribute__((ext_vector_type(4)));
union HU { v8h h; uint4 u; };

// ---------------- merged prep: binarize w1/w2/w3/w4 + pack w0 MFMA B-fragments ----------------
// blocks 0..1151 -> w1, 1152..2303 -> w2, 2304..3455 -> w3, 3456..3583 -> w4,
// 3584..3591 -> B-frags: nt = id-3584; lane holds B[k=(lane>>4)*8+j][n=nt*16+(lane&15)]
__global__ void prep_all(const float* __restrict__ w0, const float* __restrict__ w1,
                         const float* __restrict__ w2, const float* __restrict__ w3,
                         const float* __restrict__ w4,
                         unsigned long long* __restrict__ wb1, unsigned long long* __restrict__ wb2,
                         unsigned long long* __restrict__ wb3, unsigned long long* __restrict__ wb4,
                         _Float16* __restrict__ bsig, _Float16* __restrict__ babs) {
    int id = blockIdx.x, lane = threadIdx.x;
    if (id < 3456) {
        const float* w = id < 1152 ? w1 : (id < 2304 ? w2 : w3);
        unsigned long long* o = id < 1152 ? wb1 : (id < 2304 ? wb2 : wb3);
        int item = id % 1152;
        int oc = item / 9, k = item % 9;
        const float* base = w + (size_t)oc * 1152 + k;   // element ic at base[ic*9]
        unsigned long long b0 = __ballot(base[lane * 9] >= 0.f);
        unsigned long long b1 = __ballot(base[(lane + 64) * 9] >= 0.f);
        if (lane == 0) { o[item * 2] = b0; o[item * 2 + 1] = b1; }
    } else if (id < 3584) {
        int oc = id - 3456;
        unsigned long long b0 = __ballot(w4[oc * 128 + lane] >= 0.f);
        unsigned long long b1 = __ballot(w4[oc * 128 + lane + 64] >= 0.f);
        if (lane == 0) { wb4[oc * 2] = b0; wb4[oc * 2 + 1] = b1; }
    } else {
        int nt = id - 3584;                 // 0..7
        int n = nt * 16 + (lane & 15);
        int k0 = (lane >> 4) * 8;
#pragma unroll
        for (int j = 0; j < 8; j++) {
            int k = k0 + j;
            float v = (k < 27) ? w0[n * 27 + k] : 0.f;
            bsig[(nt * 64 + lane) * 8 + j] = (_Float16)v;
            babs[(nt * 64 + lane) * 8 + j] = (_Float16)fabsf(v);
        }
    }
}

// ---- one block per batch element ----
// __launch_bounds__(256,4): 4 waves/EU => 128-VGPR budget, 4 blocks/CU — forbids
// the 60-VGPR spill allocation the default heuristic chose in round 8.
__global__ __launch_bounds__(256, 4) void fused_net(
    const float* __restrict__ x, const float* __restrict__ w0,
    const _Float16* __restrict__ bsigG, const _Float16* __restrict__ babsG,
    const unsigned long long* __restrict__ wb1, const unsigned long long* __restrict__ wb2,
    const unsigned long long* __restrict__ wb3, const unsigned long long* __restrict__ wb4,
    const float* __restrict__ w5, float* __restrict__ out) {
    __shared__ float xs[3072];                 // input image (12 KB)
    __shared__ unsigned char S[14592];         // [mt57][nt4][lane64] sign|flag bits
    __shared__ alignas(16) unsigned long long bits1[450];  // [15*15][2]
    __shared__ alignas(16) unsigned long long bits2[72];
    __shared__ unsigned long long bits3[18];
    __shared__ unsigned long long bits4[2];
    __shared__ float r_s[128];
    __shared__ float l_s[NUM_CLS];
    __shared__ float e_s[NUM_CLS];
    __shared__ unsigned int qcnt;
    __shared__ unsigned int queue[1024];

    int b = blockIdx.x;
    int tid = threadIdx.x;
    int lane = tid & 63, wave = tid >> 6;

    // ================= phase 0: conv0 via f16 MFMA + guard + maxpool2 + pack =================
    {
        const float* xb = x + (size_t)b * 3072;
        for (int i = tid; i < 3072; i += 256) xs[i] = xb[i];   // coalesced

        // per-lane A-gather offsets: k = k0+j -> (c,ky,kx); addr = (oy*32+ox) + off
        int k0 = (lane >> 4) * 8;
        int offj[8];
#pragma unroll
        for (int j = 0; j < 8; j++) {
            int k = k0 + j;
            int c = k / 9, r = (k % 9) / 3, q = k % 3;
            offj[j] = c * 1024 + r * 32 + q;
        }
        const uint4* bs4 = (const uint4*)bsigG;
        const uint4* ba4 = (const uint4*)babsG;
        int col = lane & 15, nt4l = lane >> 4;

        for (int pass = 0; pass < 2; pass++) {     // pass 0: oc 0-63, pass 1: oc 64-127
            if (tid == 0) qcnt = 0;
            __syncthreads();                       // staging/S-reuse + qcnt visible
            HU bfs[4], bfa[4];
#pragma unroll
            for (int nt = 0; nt < 4; nt++) {
                bfs[nt].u = bs4[(pass * 4 + nt) * 64 + lane];
                bfa[nt].u = ba4[(pass * 4 + nt) * 64 + lane];
            }
            for (int mt = wave; mt < 57; mt += 4) {   // M=900 -> 57 tiles of 16
                int m = mt * 16 + (lane & 15);
                int me = m < 900 ? m : 899;           // pad rows read junk, discarded
                int oy = me / 30, ox = me - oy * 30;
                int base = oy * 32 + ox;
                v8h a;
#pragma unroll
                for (int j = 0; j < 8; j++) {
                    float v = (k0 + j < 27) ? xs[base + offj[j]] : 0.f;
                    a[j] = (_Float16)v;
                }
                HU ua; ua.h = a;                      // |A| for the error-bound MFMA
                ua.u.x &= 0x7FFF7FFFu; ua.u.y &= 0x7FFF7FFFu;
                ua.u.z &= 0x7FFF7FFFu; ua.u.w &= 0x7FFF7FFFu;
#pragma unroll
                for (int nt = 0; nt < 4; nt++) {
                    v4f s  = __builtin_amdgcn_mfma_f32_16x16x32_f16(a,    bfs[nt].h, (v4f){0.f,0.f,0.f,0.f}, 0, 0, 0);
                    v4f sa = __builtin_amdgcn_mfma_f32_16x16x32_f16(ua.h, bfa[nt].h, (v4f){0.f,0.f,0.f,0.f}, 0, 0, 0);
                    unsigned int byte = 0;
#pragma unroll
                    for (int reg = 0; reg < 4; reg++) {
                        float bd = fmaf(sa[reg], 1.1e-3f, 1e-5f);   // rigorous f16-rounding bound
                        if (s[reg] >= bd) byte |= 1u << reg;        // certain positive
                        if (fabsf(s[reg]) < bd) byte |= 1u << (4 + reg);  // uncertain
                    }
                    S[(mt * 4 + nt) * 64 + lane] = (unsigned char)byte;
                }
            }
            __syncthreads();
            // ---- pool (OR of signs over 2x2) + optimistic pack + uncertainty queue ----
            for (int p = wave; p < 225; p += 4) {
                int py = p / 15, pxx = p - py * 15;
                int m00 = py * 60 + pxx * 2;
                unsigned int cpAny = 0, fmask = 0;
#pragma unroll
                for (int dm = 0; dm < 4; dm++) {
                    int m = m00 + (dm >> 1) * 30 + (dm & 1);
                    unsigned int bt = S[((m >> 4) * 4 + nt4l) * 64 + (((m & 15) >> 2) << 4) + col];
                    unsigned int bi = m & 3;
                    cpAny |= (bt >> bi) & 1u;
                    fmask |= ((bt >> (4 + bi)) & 1u) << dm;
                }
                unsigned long long mw = __ballot(cpAny != 0);
                if (lane == 0) bits1[p * 2 + pass] = mw;
                if (!cpAny && fmask) {               // only unresolved windows queue (~50/img)
                    unsigned int qi = atomicAdd(&qcnt, 1u);
                    if (qi < 1024) queue[qi] = (unsigned)p | ((unsigned)(pass * 64 + lane) << 8) | (fmask << 16);
                }
            }
            __syncthreads();
            // ---- drain queue: exact f64 signs for uncertain values ----
            unsigned int nq = qcnt < 1024u ? qcnt : 1024u;
            for (unsigned int i = tid; i < nq; i += 256) {
                unsigned int e = queue[i];
                int p = e & 255; int oc = (e >> 8) & 255; unsigned int fm = (e >> 16) & 15u;
                int py = p / 15, pxx = p - py * 15;
                bool pos = false;
#pragma unroll
                for (int dm = 0; dm < 4; dm++) {
                    if (!(fm & (1u << dm))) continue;
                    int m = py * 60 + pxx * 2 + (dm >> 1) * 30 + (dm & 1);
                    int oy = m / 30, ox = m - oy * 30;
                    double sd = 0.0;
#pragma unroll
                    for (int k = 0; k < 27; k++) {
                        int c = k / 9, r = (k % 9) / 3, q = k % 3;
                        sd += (double)xs[c * 1024 + (oy + r) * 32 + ox + q] * (double)w0[oc * 27 + k];
                    }
                    pos |= (sd >= 0.0);
                }
                if (pos) atomicOr(&bits1[p * 2 + (oc >> 6)], 1ull << (oc & 63));
            }
        }
    }
    __syncthreads();

    int wave2 = tid >> 6, half = wave2 & 1, pair = wave2 >> 1;
    int oc = half * 64 + lane;

    // ================= phase 1: binconv1 (15->13) + maxpool2 (->6) =================
    // row-decomposed: per 4x4-patch row load 4x ulonglong2 (b128), scatter taps into
    // the 4 pool-window partial popcounts -> ~80 live VGPRs, no spill.
    {
        unsigned long long wr[18];
#pragma unroll
        for (int j = 0; j < 18; j++) wr[j] = wb1[oc * 18 + j];
        const ulonglong2* b1v = (const ulonglong2*)bits1;
        for (int p = pair; p < 36; p += 2) {
            int py = p / 6, px = p % 6;
            int P0 = 0, P1 = 0, P2 = 0, P3 = 0;
#pragma unroll
            for (int yy = 0; yy < 4; yy++) {
                int rb = (2 * py + yy) * 15 + 2 * px;
                ulonglong2 q0 = b1v[rb];
                ulonglong2 q1 = b1v[rb + 1];
                ulonglong2 q2 = b1v[rb + 2];
                ulonglong2 q3 = b1v[rb + 3];
#pragma unroll
                for (int dy = 0; dy < 2; dy++) {
                    int ky = yy - dy;
                    if (ky < 0 || ky > 2) continue;
#pragma unroll
                    for (int kx = 0; kx < 3; kx++) {
                        ulonglong2 qa = kx == 0 ? q0 : (kx == 1 ? q1 : q2);
                        ulonglong2 qb = kx == 0 ? q1 : (kx == 1 ? q2 : q3);
                        int d0 = __popcll(qa.x ^ wr[(ky * 3 + kx) * 2]) +
                                 __popcll(qa.y ^ wr[(ky * 3 + kx) * 2 + 1]);
                        int d1 = __popcll(qb.x ^ wr[(ky * 3 + kx) * 2]) +
                                 __popcll(qb.y ^ wr[(ky * 3 + kx) * 2 + 1]);
                        if (dy == 0) { P0 += d0; P1 += d1; }
                        else         { P2 += d0; P3 += d1; }
                    }
                }
            }
            bool pos = (P0 <= 576) | (P1 <= 576) | (P2 <= 576) | (P3 <= 576);
            unsigned long long m = __ballot(pos);
            if (lane == 0) bits2[p * 2 + half] = m;
        }
    }
    __syncthreads();

    // ================= phase 2: binconv2 (6->4) + maxpool(2,s1) (->3) =================
    {
        unsigned long long wr[18];
#pragma unroll
        for (int j = 0; j < 18; j++) wr[j] = wb2[oc * 18 + j];
        const ulonglong2* b2v = (const ulonglong2*)bits2;
        for (int p = pair; p < 9; p += 2) {
            int py = p / 3, px = p % 3;
            bool pos = false;
#pragma unroll
            for (int dy = 0; dy < 2; dy++)
#pragma unroll
                for (int dx = 0; dx < 2; dx++) {
                    int P = 0;
#pragma unroll
                    for (int ky = 0; ky < 3; ky++)
#pragma unroll
                        for (int kx = 0; kx < 3; kx++) {
                            ulonglong2 q = b2v[(py + dy + ky) * 6 + (px + dx + kx)];
                            P += __popcll(q.x ^ wr[(ky * 3 + kx) * 2]);
                            P += __popcll(q.y ^ wr[(ky * 3 + kx) * 2 + 1]);
                        }
                    pos |= (P <= 576);
                }
            unsigned long long m = __ballot(pos);
            if (lane == 0) bits3[p * 2 + half] = m;
        }
    }
    __syncthreads();

    // ================= phase 3: binconv3 + binconv4 + relu + w5 + softmax =================
    if (tid < 128) {
        int P = 0;
#pragma unroll
        for (int k = 0; k < 9; k++) {
            P += __popcll(bits3[k * 2] ^ wb3[tid * 18 + k * 2]);
            P += __popcll(bits3[k * 2 + 1] ^ wb3[tid * 18 + k * 2 + 1]);
        }
        unsigned long long m = __ballot(P <= 576);
        if ((tid & 63) == 0) bits4[tid >> 6] = m;
    }
    __syncthreads();
    if (tid < 128) {
        unsigned long long i0 = bits4[0], i1 = bits4[1];
        int v = 128 - 2 * (int)(__popcll(i0 ^ wb4[tid * 2]) + __popcll(i1 ^ wb4[tid * 2 + 1]));
        r_s[tid] = v > 0 ? (float)v : 0.f;   // relu
    }
    __syncthreads();
    if (tid < NUM_CLS) {
        float l = 0.f;
#pragma unroll 8
        for (int k = 0; k < 128; k++) l = fmaf(w5[tid * 128 + k], r_s[k], l);
        l_s[tid] = l;
    }
    __syncthreads();
    if (tid < NUM_CLS) {
        float mx = -1e30f;
        for (int k = 0; k < NUM_CLS; k++) mx = fmaxf(mx, l_s[k]);
        e_s[tid] = expf(l_s[tid] - mx);
    }
    __syncthreads();
    if (tid < NUM_CLS) {
        float sum = 0.f;
        for (int k = 0; k < NUM_CLS; k++) sum += e_s[k];
        out[(size_t)b * NUM_CLS + tid] = e_s[tid] / sum;
    }
}

extern "C" void kernel_launch(void* const* d_in, const int* in_sizes, int n_in,
                              void* d_out, int out_size, void* d_ws, size_t ws_size,
                              hipStream_t stream) {
    const float* x  = (const float*)d_in[0];
    const float* w0 = (const float*)d_in[1];
    const float* w1 = (const float*)d_in[2];
    const float* w2 = (const float*)d_in[3];
    const float* w3 = (const float*)d_in[4];
    const float* w4 = (const float*)d_in[5];
    const float* w5 = (const float*)d_in[6];
    float* out = (float*)d_out;

    int B = in_sizes[0] / 3072;   // 1024

    size_t off = 0;
    auto carve = [&](size_t bytes) {
        void* p = (char*)d_ws + off;
        off += (bytes + 255) & ~(size_t)255;
        return p;
    };
    unsigned long long* wb1 = (unsigned long long*)carve(1152 * 2 * 8);
    unsigned long long* wb2 = (unsigned long long*)carve(1152 * 2 * 8);
    unsigned long long* wb3 = (unsigned long long*)carve(1152 * 2 * 8);
    unsigned long long* wb4 = (unsigned long long*)carve(128 * 2 * 8);
    _Float16* bsig = (_Float16*)carve(8 * 64 * 8 * 2);   // MFMA B-frags (signed)
    _Float16* babs = (_Float16*)carve(8 * 64 * 8 * 2);   // MFMA B-frags (abs)
    (void)ws_size; (void)n_in; (void)out_size;

    prep_all<<<3592, 64, 0, stream>>>(w0, w1, w2, w3, w4, wb1, wb2, wb3, wb4, bsig, babs);
    fused_net<<<B, 256, 0, stream>>>(x, w0, bsig, babs, wb1, wb2, wb3, wb4, w5, out);
}

// Round 10
// 170.270 us; speedup vs baseline: 1.8369x; 1.2902x over previous
//
#include <hip/hip_runtime.h>
#include <cmath>

#define NUM_CLS 58

typedef _Float16 v8h __attribute__((ext_vector_type(8)));
typedef float v4f __attribute__((ext_vector_type(4)));
union HU { v8h h; uint4 u; };

// ---------------- merged prep: binarize w1/w2/w3/w4 + pack w0 MFMA B-fragments ----------------
// blocks 0..1151 -> w1, 1152..2303 -> w2, 2304..3455 -> w3, 3456..3583 -> w4,
// 3584..3591 -> B-frags: nt = id-3584; lane holds B[k=(lane>>4)*8+j][n=nt*16+(lane&15)]
__global__ void prep_all(const float* __restrict__ w0, const float* __restrict__ w1,
                         const float* __restrict__ w2, const float* __restrict__ w3,
                         const float* __restrict__ w4,
                         unsigned long long* __restrict__ wb1, unsigned long long* __restrict__ wb2,
                         unsigned long long* __restrict__ wb3, unsigned long long* __restrict__ wb4,
                         _Float16* __restrict__ bsig) {
    int id = blockIdx.x, lane = threadIdx.x;
    if (id < 3456) {
        const float* w = id < 1152 ? w1 : (id < 2304 ? w2 : w3);
        unsigned long long* o = id < 1152 ? wb1 : (id < 2304 ? wb2 : wb3);
        int item = id % 1152;
        int oc = item / 9, k = item % 9;
        const float* base = w + (size_t)oc * 1152 + k;   // element ic at base[ic*9]
        unsigned long long b0 = __ballot(base[lane * 9] >= 0.f);
        unsigned long long b1 = __ballot(base[(lane + 64) * 9] >= 0.f);
        if (lane == 0) { o[item * 2] = b0; o[item * 2 + 1] = b1; }
    } else if (id < 3584) {
        int oc = id - 3456;
        unsigned long long b0 = __ballot(w4[oc * 128 + lane] >= 0.f);
        unsigned long long b1 = __ballot(w4[oc * 128 + lane + 64] >= 0.f);
        if (lane == 0) { wb4[oc * 2] = b0; wb4[oc * 2 + 1] = b1; }
    } else {
        int nt = id - 3584;                 // 0..7
        int n = nt * 16 + (lane & 15);
        int k0 = (lane >> 4) * 8;
#pragma unroll
        for (int j = 0; j < 8; j++) {
            int k = k0 + j;
            float v = (k < 27) ? w0[n * 27 + k] : 0.f;
            bsig[(nt * 64 + lane) * 8 + j] = (_Float16)v;
        }
    }
}

// ---- one block per batch element ----
__global__ __launch_bounds__(256, 4) void fused_net(
    const float* __restrict__ x, const float* __restrict__ w0,
    const _Float16* __restrict__ bsigG,
    const unsigned long long* __restrict__ wb1, const unsigned long long* __restrict__ wb2,
    const unsigned long long* __restrict__ wb3, const unsigned long long* __restrict__ wb4,
    const float* __restrict__ w5, float* __restrict__ out) {
    __shared__ float xs[3072];                 // input image (12 KB)
    __shared__ uint4 bfrag[512];               // B sign-fragments, 8 nt x 64 lanes (8 KB)
    __shared__ alignas(16) unsigned long long bits1[450];  // [15*15][2]
    __shared__ alignas(16) unsigned long long bits2[72];
    __shared__ unsigned long long bits3[18];
    __shared__ unsigned long long bits4[2];
    __shared__ float r_s[128];
    __shared__ float l_s[NUM_CLS];
    __shared__ float e_s[NUM_CLS];
    __shared__ unsigned int qcnt;
    __shared__ unsigned int queue[1536];

    int b = blockIdx.x;
    int tid = threadIdx.x;
    int lane = tid & 63, wave = tid >> 6;

    // ================= phase 0: conv0 via f16 MFMA (pool-ordered im2col) =================
    // im2col row m' = p*4 + window  =>  each lane's 4 C-regs are one pooled pixel's
    // 2x2 window set for one oc: pool = OR over own regs, pack = 1 ballot per nt.
    {
        const float* xb = x + (size_t)b * 3072;
        for (int i = tid; i < 3072; i += 256) xs[i] = xb[i];   // coalesced
        const uint4* bs4 = (const uint4*)bsigG;
        for (int i = tid; i < 512; i += 256) bfrag[i] = bs4[i];
        if (tid == 0) qcnt = 0;
        __syncthreads();

        // per-lane A-gather offsets: k = k0+j -> (c,ky,kx); addr = (oy*32+ox) + off
        int k0 = (lane >> 4) * 8;
        int offj[8];
#pragma unroll
        for (int j = 0; j < 8; j++) {
            int k = k0 + j;
            int c = k / 9, r = (k % 9) / 3, q = k % 3;
            offj[j] = c * 1024 + r * 32 + q;
        }
        unsigned short* b1u16 = (unsigned short*)bits1;

        for (int mt = wave; mt < 57; mt += 4) {   // M = 225*4 = 900 -> 57 tiles
            int mg = mt * 16 + (lane & 15);       // A row this lane supplies
            int me = mg < 900 ? mg : 899;         // pad rows read junk, discarded
            int p = me >> 2, win = me & 3;
            int py = p / 15, px = p - py * 15;
            int base = (py * 2 + (win >> 1)) * 32 + px * 2 + (win & 1);
            v8h a;
#pragma unroll
            for (int j = 0; j < 8; j++) {
                float v = (k0 + j < 27) ? xs[base + offj[j]] : 0.f;
                a[j] = (_Float16)v;
            }
            HU ua; ua.h = a;                      // |A| for the error-bound MFMA
            ua.u.x &= 0x7FFF7FFFu; ua.u.y &= 0x7FFF7FFFu;
            ua.u.z &= 0x7FFF7FFFu; ua.u.w &= 0x7FFF7FFFu;
            int myp = mt * 4 + (lane >> 4);       // pooled pixel of this lane's C-regs
#pragma unroll
            for (int nt = 0; nt < 8; nt++) {
                HU bs; bs.u = bfrag[nt * 64 + lane];
                HU ba; ba.u.x = bs.u.x & 0x7FFF7FFFu; ba.u.y = bs.u.y & 0x7FFF7FFFu;
                       ba.u.z = bs.u.z & 0x7FFF7FFFu; ba.u.w = bs.u.w & 0x7FFF7FFFu;
                v4f s  = __builtin_amdgcn_mfma_f32_16x16x32_f16(a,    bs.h, (v4f){0.f,0.f,0.f,0.f}, 0, 0, 0);
                v4f sa = __builtin_amdgcn_mfma_f32_16x16x32_f16(ua.h, ba.h, (v4f){0.f,0.f,0.f,0.f}, 0, 0, 0);
                bool pos = false; unsigned int fm = 0;
#pragma unroll
                for (int reg = 0; reg < 4; reg++) {
                    float bd = fmaf(sa[reg], 1.1e-3f, 1e-5f);   // rigorous f16-rounding bound
                    pos |= (s[reg] >= bd);                       // certain positive
                    fm  |= (fabsf(s[reg]) < bd) ? (1u << reg) : 0u;  // uncertain (win=reg)
                }
                unsigned long long mk = __ballot(pos);
                if ((lane & 15) == 0 && myp < 225)
                    b1u16[myp * 8 + nt] = (unsigned short)(mk >> (lane & 48));
                if (!pos && fm && myp < 225) {    // unresolved -> exact f64 later
                    unsigned int qi = atomicAdd(&qcnt, 1u);
                    if (qi < 1536) queue[qi] = (unsigned)myp | ((unsigned)(nt * 16 + (lane & 15)) << 8) | (fm << 16);
                }
            }
        }
        __syncthreads();
        // ---- drain queue: exact f64 signs for uncertain values ----
        unsigned int nq = qcnt < 1536u ? qcnt : 1536u;
        for (unsigned int i = tid; i < nq; i += 256) {
            unsigned int e = queue[i];
            int p = e & 255; int oc = (e >> 8) & 255; unsigned int fm = (e >> 16) & 15u;
            int py = p / 15, px = p - py * 15;
            bool pos = false;
#pragma unroll
            for (int win = 0; win < 4; win++) {
                if (!(fm & (1u << win))) continue;
                int base = (py * 2 + (win >> 1)) * 32 + px * 2 + (win & 1);
                double sd = 0.0;
#pragma unroll
                for (int k = 0; k < 27; k++) {
                    int c = k / 9, r = (k % 9) / 3, q = k % 3;
                    sd += (double)xs[base + c * 1024 + r * 32 + q] * (double)w0[oc * 27 + k];
                }
                pos |= (sd >= 0.0);
            }
            if (pos) atomicOr(&bits1[p * 2 + (oc >> 6)], 1ull << (oc & 63));
        }
    }
    __syncthreads();

    int wave2 = tid >> 6, half = wave2 & 1, pair = wave2 >> 1;
    int oc = half * 64 + lane;

    // ================= phase 1: binconv1 (15->13) + maxpool2 (->6) =================
    {
        unsigned long long wr[18];
#pragma unroll
        for (int j = 0; j < 18; j++) wr[j] = wb1[oc * 18 + j];
        const ulonglong2* b1v = (const ulonglong2*)bits1;
        for (int p = pair; p < 36; p += 2) {
            int py = p / 6, px = p % 6;
            int P0 = 0, P1 = 0, P2 = 0, P3 = 0;
#pragma unroll
            for (int yy = 0; yy < 4; yy++) {
                int rb = (2 * py + yy) * 15 + 2 * px;
                ulonglong2 q0 = b1v[rb];
                ulonglong2 q1 = b1v[rb + 1];
                ulonglong2 q2 = b1v[rb + 2];
                ulonglong2 q3 = b1v[rb + 3];
#pragma unroll
                for (int dy = 0; dy < 2; dy++) {
                    int ky = yy - dy;
                    if (ky < 0 || ky > 2) continue;
#pragma unroll
                    for (int kx = 0; kx < 3; kx++) {
                        ulonglong2 qa = kx == 0 ? q0 : (kx == 1 ? q1 : q2);
                        ulonglong2 qb = kx == 0 ? q1 : (kx == 1 ? q2 : q3);
                        int d0 = __popcll(qa.x ^ wr[(ky * 3 + kx) * 2]) +
                                 __popcll(qa.y ^ wr[(ky * 3 + kx) * 2 + 1]);
                        int d1 = __popcll(qb.x ^ wr[(ky * 3 + kx) * 2]) +
                                 __popcll(qb.y ^ wr[(ky * 3 + kx) * 2 + 1]);
                        if (dy == 0) { P0 += d0; P1 += d1; }
                        else         { P2 += d0; P3 += d1; }
                    }
                }
            }
            bool pos = (P0 <= 576) | (P1 <= 576) | (P2 <= 576) | (P3 <= 576);
            unsigned long long m = __ballot(pos);
            if (lane == 0) bits2[p * 2 + half] = m;
        }
    }
    __syncthreads();

    // ================= phase 2: binconv2 (6->4) + maxpool(2,s1) (->3) =================
    {
        unsigned long long wr[18];
#pragma unroll
        for (int j = 0; j < 18; j++) wr[j] = wb2[oc * 18 + j];
        const ulonglong2* b2v = (const ulonglong2*)bits2;
        for (int p = pair; p < 9; p += 2) {
            int py = p / 3, px = p % 3;
            bool pos = false;
#pragma unroll
            for (int dy = 0; dy < 2; dy++)
#pragma unroll
                for (int dx = 0; dx < 2; dx++) {
                    int P = 0;
#pragma unroll
                    for (int ky = 0; ky < 3; ky++)
#pragma unroll
                        for (int kx = 0; kx < 3; kx++) {
                            ulonglong2 q = b2v[(py + dy + ky) * 6 + (px + dx + kx)];
                            P += __popcll(q.x ^ wr[(ky * 3 + kx) * 2]);
                            P += __popcll(q.y ^ wr[(ky * 3 + kx) * 2 + 1]);
                        }
                    pos |= (P <= 576);
                }
            unsigned long long m = __ballot(pos);
            if (lane == 0) bits3[p * 2 + half] = m;
        }
    }
    __syncthreads();

    // ================= phase 3: binconv3 + binconv4 + relu + w5 + softmax =================
    if (tid < 128) {
        int P = 0;
#pragma unroll
        for (int k = 0; k < 9; k++) {
            P += __popcll(bits3[k * 2] ^ wb3[tid * 18 + k * 2]);
            P += __popcll(bits3[k * 2 + 1] ^ wb3[tid * 18 + k * 2 + 1]);
        }
        unsigned long long m = __ballot(P <= 576);
        if ((tid & 63) == 0) bits4[tid >> 6] = m;
    }
    __syncthreads();
    if (tid < 128) {
        unsigned long long i0 = bits4[0], i1 = bits4[1];
        int v = 128 - 2 * (int)(__popcll(i0 ^ wb4[tid * 2]) + __popcll(i1 ^ wb4[tid * 2 + 1]));
        r_s[tid] = v > 0 ? (float)v : 0.f;   // relu
    }
    __syncthreads();
    if (tid < NUM_CLS) {
        float l = 0.f;
#pragma unroll 8
        for (int k = 0; k < 128; k++) l = fmaf(w5[tid * 128 + k], r_s[k], l);
        l_s[tid] = l;
    }
    __syncthreads();
    if (tid < NUM_CLS) {
        float mx = -1e30f;
        for (int k = 0; k < NUM_CLS; k++) mx = fmaxf(mx, l_s[k]);
        e_s[tid] = expf(l_s[tid] - mx);
    }
    __syncthreads();
    if (tid < NUM_CLS) {
        float sum = 0.f;
        for (int k = 0; k < NUM_CLS; k++) sum += e_s[k];
        out[(size_t)b * NUM_CLS + tid] = e_s[tid] / sum;
    }
}

extern "C" void kernel_launch(void* const* d_in, const int* in_sizes, int n_in,
                              void* d_out, int out_size, void* d_ws, size_t ws_size,
                              hipStream_t stream) {
    const float* x  = (const float*)d_in[0];
    const float* w0 = (const float*)d_in[1];
    const float* w1 = (const float*)d_in[2];
    const float* w2 = (const float*)d_in[3];
    const float* w3 = (const float*)d_in[4];
    const float* w4 = (const float*)d_in[5];
    const float* w5 = (const float*)d_in[6];
    float* out = (float*)d_out;

    int B = in_sizes[0] / 3072;   // 1024

    size_t off = 0;
    auto carve = [&](size_t bytes) {
        void* p = (char*)d_ws + off;
        off += (bytes + 255) & ~(size_t)255;
        return p;
    };
    unsigned long long* wb1 = (unsigned long long*)carve(1152 * 2 * 8);
    unsigned long long* wb2 = (unsigned long long*)carve(1152 * 2 * 8);
    unsigned long long* wb3 = (unsigned long long*)carve(1152 * 2 * 8);
    unsigned long long* wb4 = (unsigned long long*)carve(128 * 2 * 8);
    _Float16* bsig = (_Float16*)carve(8 * 64 * 8 * 2);   // MFMA B-frags (signed)
    (void)ws_size; (void)n_in; (void)out_size;

    prep_all<<<3592, 64, 0, stream>>>(w0, w1, w2, w3, w4, wb1, wb2, wb3, wb4, bsig);
    fused_net<<<B, 256, 0, stream>>>(x, w0, bsig, wb1, wb2, wb3, wb4, w5, out);
}